// Round 3
// baseline (226.529 us; speedup 1.0000x reference)
//
#include <hip/hip_runtime.h>

// YOLO layer: (64, 3*85, 44, 44) -> (64, 3*44*44, 85), fp32.
// Memory-bound: 253 MB traffic -> ~40 us roofline @ 6.3 TB/s.
// R2 (81 us, 2.55 TB/s): latency/in-flight OK but DRAM-inefficient —
// 256 B read granules + round-robin XCD dispatch interleaving adjacent tiles
// across XCDs. R3: 128-spatial tiles (512 B granules), XCD-contiguous block
// swizzle, non-temporal stores.

#define BSZ      64
#define NA       3
#define NC       80
#define GRID     44
#define SPATIAL  (GRID * GRID)       // 1936
#define CH       (5 + NC)            // 85
#define TILE     128
#define TILES_PER_BA ((SPATIAL + TILE - 1) / TILE)   // 16 (last tile: 16 valid)
#define LDSS     89                  // [s][c] row stride (floats)
#define NF       (CH * (TILE / 4))   // 2720 float4 loads per block
#define BLK      512
#define NITER    ((NF + BLK - 1) / BLK)  // 6
#define NXCD     8
#define STRIDE_F 8.0f                // 352/44; cancels /STRIDE in scaled anchors

__device__ __forceinline__ float sigf(float x) {
    return 1.0f / (1.0f + __expf(-x));
}

__global__ __launch_bounds__(BLK, 6)
void yolo_kernel(const float* __restrict__ in, float* __restrict__ out) {
    __shared__ float tile[TILE * LDSS];   // 128*89*4 = 45,568 B -> 3 blocks/CU

    // XCD swizzle: HW assigns consecutive blockIdx round-robin to 8 XCDs.
    // Remap so each XCD owns a contiguous range of logical tiles (sequential
    // DRAM streams per XCD). grid = 3072 = 8 * 384.
    const int nper = gridDim.x / NXCD;                     // 384
    const int bid  = (blockIdx.x % NXCD) * nper + blockIdx.x / NXCD;

    const int t   = bid % TILES_PER_BA;
    const int ba  = bid / TILES_PER_BA;   // b*NA + a
    const int a   = ba % NA;

    const int s0    = t * TILE;
    const int valid = min(TILE, SPATIAL - s0);   // 128 or 16 (mult of 4)

    const float aw = (a == 0) ? 10.0f : (a == 1) ? 16.0f : 33.0f;
    const float ah = (a == 0) ? 13.0f : (a == 1) ? 30.0f : 23.0f;

    const int tid = threadIdx.x;
    const float* inbase = in + (size_t)ba * CH * SPATIAL + s0;

    // ---- phase 1a: issue ALL global loads first (bytes in flight) ----
    // f -> (channel c = f>>5, spatial-quad q = f&31): each 32-lane group reads
    // 512 B contiguous from one channel row.
    float4 v[NITER];
    #pragma unroll
    for (int i = 0; i < NITER; ++i) {
        int f = tid + i * BLK;
        int c = f >> 5, q = f & 31;
        if (f < NF && q * 4 < valid)
            v[i] = *(const float4*)(inbase + (size_t)c * SPATIAL + q * 4);
    }

    // ---- phase 1b: transform + LDS transpose write ----
    #pragma unroll
    for (int i = 0; i < NITER; ++i) {
        int f = tid + i * BLK;
        int c = f >> 5, q = f & 31;
        if (f >= NF || q * 4 >= valid) continue;
        float r[4] = {v[i].x, v[i].y, v[i].z, v[i].w};
        #pragma unroll
        for (int j = 0; j < 4; ++j) {
            int   sl = q * 4 + j;         // local spatial
            int   gs = s0 + sl;           // global spatial
            float x  = r[j];
            float o;
            if (c == 0)      o = (sigf(x) + (float)(gs % GRID)) * STRIDE_F;
            else if (c == 1) o = (sigf(x) + (float)(gs / GRID)) * STRIDE_F;
            else if (c == 2) o = __expf(x) * aw;
            else if (c == 3) o = __expf(x) * ah;
            else             o = sigf(x);  // conf + 80 classes
            tile[sl * LDSS + c] = o;
        }
    }
    __syncthreads();

    // ---- phase 2: coalesced contiguous non-temporal stores ----
    const size_t obase = ((size_t)ba * SPATIAL + s0) * CH;
    const int total = valid * CH;         // 10880 (full) / 1360 (tail)
    #pragma unroll 4
    for (int k = tid; k < total; k += BLK) {
        int s = k / CH;                   // const-divisor -> magic-mul
        int c = k - s * CH;
        __builtin_nontemporal_store(tile[s * LDSS + c], &out[obase + k]);
    }
}

extern "C" void kernel_launch(void* const* d_in, const int* in_sizes, int n_in,
                              void* d_out, int out_size, void* d_ws, size_t ws_size,
                              hipStream_t stream) {
    const float* in = (const float*)d_in[0];
    float* out = (float*)d_out;
    const int grid = BSZ * NA * TILES_PER_BA;   // 3072 blocks = 8 XCD * 384
    yolo_kernel<<<grid, BLK, 0, stream>>>(in, out);
}